// Round 1
// baseline (269.679 us; speedup 1.0000x reference)
//
#include <hip/hip_runtime.h>
#include <math.h>

#define N 2048
#define D 512
#define KC 8            // instances per class
#define M (KC - 1)      // positives per row
#define NNEG (N - KC)   // negatives per row
#define ALPHA 4.0f
#define THRESH 0.693f

// ---------------- Kernel 1: x = ALPHA * normalize(inputs); sq[i] = sum(x[i]^2) ----------------
__global__ __launch_bounds__(128) void normalize_kernel(const float* __restrict__ in,
                                                        float* __restrict__ x,
                                                        float* __restrict__ sq) {
    int row = blockIdx.x;
    int tid = threadIdx.x;               // 128 threads
    const float* r = in + (size_t)row * D;
    float p = 0.f;
    for (int d = tid; d < D; d += 128) { float v = r[d]; p += v * v; }
    __shared__ float red[128];
    red[tid] = p; __syncthreads();
    for (int s = 64; s > 0; s >>= 1) { if (tid < s) red[tid] += red[tid + s]; __syncthreads(); }
    float scale = ALPHA / sqrtf(red[0]);
    __syncthreads();                     // all threads have read red[0]
    float q = 0.f;
    for (int d = tid; d < D; d += 128) {
        float v = r[d] * scale;
        x[(size_t)row * D + d] = v;
        q += v * v;
    }
    red[tid] = q; __syncthreads();
    for (int s = 64; s > 0; s >>= 1) { if (tid < s) red[tid] += red[tid + s]; __syncthreads(); }
    if (tid == 0) sq[row] = red[0];
}

// ---------------- Kernel 2: dist[i][j] = sq[i] + sq[j] - 2 * dot(x_i, x_j) ----------------
// fp32 tile GEMM: 64x64 block tile, 256 threads, each computes 4x4, BK=16.
#define BM 64
#define BN 64
#define BK 16

__global__ __launch_bounds__(256) void gemm_dist_kernel(const float* __restrict__ x,
                                                        const float* __restrict__ sq,
                                                        float* __restrict__ dist) {
    __shared__ float As[BK][BM + 4];   // [k][m], padded
    __shared__ float Bs[BK][BN + 4];
    int bi = blockIdx.y, bj = blockIdx.x;
    int tid = threadIdx.x;
    int tx = tid & 15, ty = tid >> 4;

    float acc[4][4] = {};
    int lrow = tid >> 2;               // 0..63
    int lseg = (tid & 3) * 4;          // 0,4,8,12
    const float* aptr = x + ((size_t)(bi * BM + lrow)) * D + lseg;
    const float* bptr = x + ((size_t)(bj * BN + lrow)) * D + lseg;

    for (int k0 = 0; k0 < D; k0 += BK) {
        float4 av = *(const float4*)(aptr + k0);
        float4 bv = *(const float4*)(bptr + k0);
        As[lseg + 0][lrow] = av.x; As[lseg + 1][lrow] = av.y;
        As[lseg + 2][lrow] = av.z; As[lseg + 3][lrow] = av.w;
        Bs[lseg + 0][lrow] = bv.x; Bs[lseg + 1][lrow] = bv.y;
        Bs[lseg + 2][lrow] = bv.z; Bs[lseg + 3][lrow] = bv.w;
        __syncthreads();
        #pragma unroll
        for (int k = 0; k < BK; ++k) {
            float4 a4 = *(const float4*)&As[k][ty * 4];
            float4 b4 = *(const float4*)&Bs[k][tx * 4];
            float a[4] = {a4.x, a4.y, a4.z, a4.w};
            float b[4] = {b4.x, b4.y, b4.z, b4.w};
            #pragma unroll
            for (int i = 0; i < 4; ++i)
                #pragma unroll
                for (int j = 0; j < 4; ++j)
                    acc[i][j] = fmaf(a[i], b[j], acc[i][j]);
        }
        __syncthreads();
    }

    int row0 = bi * BM + ty * 4;
    int col0 = bj * BN + tx * 4;
    float sj0 = sq[col0 + 0], sj1 = sq[col0 + 1], sj2 = sq[col0 + 2], sj3 = sq[col0 + 3];
    #pragma unroll
    for (int i = 0; i < 4; ++i) {
        float si = sq[row0 + i];
        float4 o;
        o.x = si + sj0 - 2.f * acc[i][0];
        o.y = si + sj1 - 2.f * acc[i][1];
        o.z = si + sj2 - 2.f * acc[i][2];
        o.w = si + sj3 - 2.f * acc[i][3];
        *(float4*)&dist[(size_t)(row0 + i) * N + col0] = o;
    }
}

// ---------------- Kernel 3: per-row triplet reduction ----------------
// acc layout (all 8-byte slots): [0] dbl sum_row_mean, [1] dbl pos_sum, [2] dbl neg_sum,
//                                [3] ull total_cnt,    [4] ull zero_rows
__global__ void init_acc_kernel(unsigned long long* acc) {
    if (threadIdx.x < 8) acc[threadIdx.x] = 0ull;
}

__global__ __launch_bounds__(256) void triplet_kernel(const float* __restrict__ dist,
                                                      double* __restrict__ accd) {
    int i = blockIdx.x;
    int tid = threadIdx.x;
    int cs = (i >> 3) << 3;            // class block start (K=8)
    const float* drow = dist + (size_t)i * N;

    __shared__ float pos[M];
    if (tid == 0) {
        int c = 0;
        for (int j = cs; j < cs + KC; ++j)
            if (j != i) pos[c++] = drow[j];
    }
    __syncthreads();
    float p[M];
    #pragma unroll
    for (int k = 0; k < M; ++k) p[k] = pos[k];

    float s = 0.f, nsum = 0.f;
    unsigned cnt = 0;
    for (int j = tid; j < N; j += 256) {
        if (j >= cs && j < cs + KC) continue;
        float neg = drow[j];
        nsum += neg;
        #pragma unroll
        for (int k = 0; k < M; ++k) {
            float t = log1pf(expf(p[k] - neg));   // matches reference log1p(exp(.))
            if (t > THRESH) { cnt++; s += t; }
        }
    }

    __shared__ float rs[256];
    __shared__ float rn[256];
    __shared__ unsigned rc[256];
    rs[tid] = s; rn[tid] = nsum; rc[tid] = cnt;
    __syncthreads();
    for (int st = 128; st > 0; st >>= 1) {
        if (tid < st) { rs[tid] += rs[tid + st]; rn[tid] += rn[tid + st]; rc[tid] += rc[tid + st]; }
        __syncthreads();
    }
    if (tid == 0) {
        unsigned c = rc[0];
        float row_mean = (c > 0) ? (rs[0] / (float)c) : 0.f;
        float psum = 0.f;
        #pragma unroll
        for (int k = 0; k < M; ++k) psum += p[k];
        atomicAdd(&accd[0], (double)row_mean);
        atomicAdd(&accd[1], (double)psum);
        atomicAdd(&accd[2], (double)rn[0]);
        atomicAdd((unsigned long long*)&accd[3], (unsigned long long)c);
        atomicAdd((unsigned long long*)&accd[4], (unsigned long long)(c == 0 ? 1u : 0u));
    }
}

// ---------------- Kernel 4: finalize scalars ----------------
__global__ void finalize_kernel(const double* __restrict__ accd, float* __restrict__ out) {
    if (threadIdx.x == 0 && blockIdx.x == 0) {
        double srm  = accd[0];
        double psum = accd[1];
        double nsum = accd[2];
        unsigned long long total = ((const unsigned long long*)accd)[3];
        unsigned long long zr    = ((const unsigned long long*)accd)[4];
        out[0] = (total > 0) ? (float)(srm / (double)total) : 0.f;        // loss
        out[1] = (float)((double)zr / (double)N);                          // accuracy
        out[2] = (float)(psum / (double)((size_t)N * M));                  // pos_d
        out[3] = (float)(nsum / (double)((size_t)N * NNEG));               // neg_d
    }
}

extern "C" void kernel_launch(void* const* d_in, const int* in_sizes, int n_in,
                              void* d_out, int out_size, void* d_ws, size_t ws_size,
                              hipStream_t stream) {
    const float* inputs = (const float*)d_in[0];
    // targets (d_in[1]) are guaranteed grouped: [0]*8,[1]*8,... — structure used directly.
    float* out = (float*)d_out;
    char* ws = (char*)d_ws;

    const size_t off_x    = 0;
    const size_t off_sq   = off_x + (size_t)N * D * sizeof(float);       // 4 MB
    const size_t off_dist = off_sq + (size_t)N * sizeof(float) + 4096;   // align
    const size_t off_acc  = off_dist + (size_t)N * N * sizeof(float);
    const size_t needed   = off_acc + 64;
    if (ws_size < needed) return;  // workspace too small — fail loudly via wrong output

    float* x    = (float*)(ws + off_x);
    float* sq   = (float*)(ws + off_sq);
    float* dist = (float*)(ws + off_dist);
    double* acc = (double*)(ws + off_acc);

    init_acc_kernel<<<1, 64, 0, stream>>>((unsigned long long*)acc);
    normalize_kernel<<<N, 128, 0, stream>>>(inputs, x, sq);
    gemm_dist_kernel<<<dim3(N / BN, N / BM), 256, 0, stream>>>(x, sq, dist);
    triplet_kernel<<<N, 256, 0, stream>>>(dist, acc);
    finalize_kernel<<<1, 64, 0, stream>>>(acc, out);
}

// Round 2
// 260.578 us; speedup vs baseline: 1.0349x; 1.0349x over previous
//
#include <hip/hip_runtime.h>
#include <math.h>

#define N 2048
#define D 512
#define KC 8            // instances per class
#define M (KC - 1)      // positives per row
#define NNEG (N - KC)   // negatives per row
#define ALPHA 4.0f
#define THRESH 0.693f
#define LN2F 0.6931471805599453f
#define INV_LN2F 1.4426950408889634f
// validity in log2 domain: log2(1+e) > THRESH/ln2
#define C2 (THRESH * INV_LN2F)

// ---------------- Kernel 1: x = ALPHA * normalize(inputs); sq[i] = sum(x[i]^2) ----------------
__global__ __launch_bounds__(128) void normalize_kernel(const float* __restrict__ in,
                                                        float* __restrict__ x,
                                                        float* __restrict__ sq) {
    int row = blockIdx.x;
    int tid = threadIdx.x;               // 128 threads
    const float* r = in + (size_t)row * D;
    float p = 0.f;
    for (int d = tid; d < D; d += 128) { float v = r[d]; p += v * v; }
    __shared__ float red[128];
    red[tid] = p; __syncthreads();
    for (int s = 64; s > 0; s >>= 1) { if (tid < s) red[tid] += red[tid + s]; __syncthreads(); }
    float scale = ALPHA / sqrtf(red[0]);
    __syncthreads();                     // all threads have read red[0]
    float q = 0.f;
    for (int d = tid; d < D; d += 128) {
        float v = r[d] * scale;
        x[(size_t)row * D + d] = v;
        q += v * v;
    }
    red[tid] = q; __syncthreads();
    for (int s = 64; s > 0; s >>= 1) { if (tid < s) red[tid] += red[tid + s]; __syncthreads(); }
    if (tid == 0) sq[row] = red[0];
}

// ---------------- Kernel 2: dist[i][j] = sq[i] + sq[j] - 2 * dot(x_i, x_j) ----------------
// fp32 tile GEMM: 64x64 block tile, 256 threads, each computes 4x4, BK=16.
#define BM 64
#define BN 64
#define BK 16

__global__ __launch_bounds__(256) void gemm_dist_kernel(const float* __restrict__ x,
                                                        const float* __restrict__ sq,
                                                        float* __restrict__ dist) {
    __shared__ float As[BK][BM + 4];   // [k][m], padded
    __shared__ float Bs[BK][BN + 4];
    int bi = blockIdx.y, bj = blockIdx.x;
    int tid = threadIdx.x;
    int tx = tid & 15, ty = tid >> 4;

    float acc[4][4] = {};
    int lrow = tid >> 2;               // 0..63
    int lseg = (tid & 3) * 4;          // 0,4,8,12
    const float* aptr = x + ((size_t)(bi * BM + lrow)) * D + lseg;
    const float* bptr = x + ((size_t)(bj * BN + lrow)) * D + lseg;

    for (int k0 = 0; k0 < D; k0 += BK) {
        float4 av = *(const float4*)(aptr + k0);
        float4 bv = *(const float4*)(bptr + k0);
        As[lseg + 0][lrow] = av.x; As[lseg + 1][lrow] = av.y;
        As[lseg + 2][lrow] = av.z; As[lseg + 3][lrow] = av.w;
        Bs[lseg + 0][lrow] = bv.x; Bs[lseg + 1][lrow] = bv.y;
        Bs[lseg + 2][lrow] = bv.z; Bs[lseg + 3][lrow] = bv.w;
        __syncthreads();
        #pragma unroll
        for (int k = 0; k < BK; ++k) {
            float4 a4 = *(const float4*)&As[k][ty * 4];
            float4 b4 = *(const float4*)&Bs[k][tx * 4];
            float a[4] = {a4.x, a4.y, a4.z, a4.w};
            float b[4] = {b4.x, b4.y, b4.z, b4.w};
            #pragma unroll
            for (int i = 0; i < 4; ++i)
                #pragma unroll
                for (int j = 0; j < 4; ++j)
                    acc[i][j] = fmaf(a[i], b[j], acc[i][j]);
        }
        __syncthreads();
    }

    int row0 = bi * BM + ty * 4;
    int col0 = bj * BN + tx * 4;
    float sj0 = sq[col0 + 0], sj1 = sq[col0 + 1], sj2 = sq[col0 + 2], sj3 = sq[col0 + 3];
    #pragma unroll
    for (int i = 0; i < 4; ++i) {
        float si = sq[row0 + i];
        float4 o;
        o.x = si + sj0 - 2.f * acc[i][0];
        o.y = si + sj1 - 2.f * acc[i][1];
        o.z = si + sj2 - 2.f * acc[i][2];
        o.w = si + sj3 - 2.f * acc[i][3];
        *(float4*)&dist[(size_t)(row0 + i) * N + col0] = o;
    }
}

// ---------------- Kernel 3: per-row triplet reduction ----------------
// acc layout (all 8-byte slots): [0] dbl sum_row_mean, [1] dbl pos_sum, [2] dbl neg_sum,
//                                [3] ull total_cnt,    [4] ull zero_rows
__global__ void init_acc_kernel(unsigned long long* acc) {
    if (threadIdx.x < 8) acc[threadIdx.x] = 0ull;
}

__global__ __launch_bounds__(256) void triplet_kernel(const float* __restrict__ dist,
                                                      double* __restrict__ accd) {
    int i = blockIdx.x;
    int tid = threadIdx.x;
    int cs = (i >> 3) << 3;            // class block start (K=8)
    const float* drow = dist + (size_t)i * N;

    __shared__ float pos[M];
    if (tid == 0) {
        int c = 0;
        for (int j = cs; j < cs + KC; ++j)
            if (j != i) pos[c++] = drow[j];
    }
    __syncthreads();
    float p[M], ep[M];
    #pragma unroll
    for (int k = 0; k < M; ++k) { p[k] = pos[k]; ep[k] = __expf(p[k]); }

    // accumulate in log2 domain: t = ln2 * log2(1 + exp(p)*exp(-n))
    float s2 = 0.f, nsum = 0.f;
    unsigned cnt = 0;
    for (int j = tid; j < N; j += 256) {
        if (j >= cs && j < cs + KC) continue;
        float neg = drow[j];
        nsum += neg;
        float en = __expf(-neg);
        #pragma unroll
        for (int k = 0; k < M; ++k) {
            float e = ep[k] * en;
            float l = __log2f(1.f + e);     // one v_log_f32
            if (l > C2) { cnt++; s2 += l; }
        }
    }

    __shared__ float rs[256];
    __shared__ float rn[256];
    __shared__ unsigned rc[256];
    rs[tid] = s2; rn[tid] = nsum; rc[tid] = cnt;
    __syncthreads();
    for (int st = 128; st > 0; st >>= 1) {
        if (tid < st) { rs[tid] += rs[tid + st]; rn[tid] += rn[tid + st]; rc[tid] += rc[tid + st]; }
        __syncthreads();
    }
    if (tid == 0) {
        unsigned c = rc[0];
        float row_mean = (c > 0) ? (rs[0] * LN2F / (float)c) : 0.f;
        float psum = 0.f;
        #pragma unroll
        for (int k = 0; k < M; ++k) psum += p[k];
        atomicAdd(&accd[0], (double)row_mean);
        atomicAdd(&accd[1], (double)psum);
        atomicAdd(&accd[2], (double)rn[0]);
        atomicAdd((unsigned long long*)&accd[3], (unsigned long long)c);
        atomicAdd((unsigned long long*)&accd[4], (unsigned long long)(c == 0 ? 1u : 0u));
    }
}

// ---------------- Kernel 4: finalize scalars ----------------
__global__ void finalize_kernel(const double* __restrict__ accd, float* __restrict__ out) {
    if (threadIdx.x == 0 && blockIdx.x == 0) {
        double srm  = accd[0];
        double psum = accd[1];
        double nsum = accd[2];
        unsigned long long total = ((const unsigned long long*)accd)[3];
        unsigned long long zr    = ((const unsigned long long*)accd)[4];
        out[0] = (total > 0) ? (float)(srm / (double)total) : 0.f;        // loss
        out[1] = (float)((double)zr / (double)N);                          // accuracy
        out[2] = (float)(psum / (double)((size_t)N * M));                  // pos_d
        out[3] = (float)(nsum / (double)((size_t)N * NNEG));               // neg_d
    }
}

extern "C" void kernel_launch(void* const* d_in, const int* in_sizes, int n_in,
                              void* d_out, int out_size, void* d_ws, size_t ws_size,
                              hipStream_t stream) {
    const float* inputs = (const float*)d_in[0];
    // targets (d_in[1]) are guaranteed grouped: [0]*8,[1]*8,... — structure used directly.
    float* out = (float*)d_out;
    char* ws = (char*)d_ws;

    const size_t off_x    = 0;
    const size_t off_sq   = off_x + (size_t)N * D * sizeof(float);       // 4 MB
    const size_t off_dist = off_sq + (size_t)N * sizeof(float) + 4096;   // align
    const size_t off_acc  = off_dist + (size_t)N * N * sizeof(float);
    const size_t needed   = off_acc + 64;
    if (ws_size < needed) return;  // workspace too small — fail loudly via wrong output

    float* x    = (float*)(ws + off_x);
    float* sq   = (float*)(ws + off_sq);
    float* dist = (float*)(ws + off_dist);
    double* acc = (double*)(ws + off_acc);

    init_acc_kernel<<<1, 64, 0, stream>>>((unsigned long long*)acc);
    normalize_kernel<<<N, 128, 0, stream>>>(inputs, x, sq);
    gemm_dist_kernel<<<dim3(N / BN, N / BM), 256, 0, stream>>>(x, sq, dist);
    triplet_kernel<<<N, 256, 0, stream>>>(dist, acc);
    finalize_kernel<<<1, 64, 0, stream>>>(acc, out);
}

// Round 3
// 140.419 us; speedup vs baseline: 1.9205x; 1.8557x over previous
//
#include <hip/hip_runtime.h>
#include <math.h>

#define N 2048
#define D 512
#define KC 8            // instances per class
#define M (KC - 1)      // positives per row
#define NNEG (N - KC)   // negatives per row
#define ALPHA 4.0f
#define THRESH 0.693f
#define LN2F 0.6931471805599453f
#define INV_LN2F 1.4426950408889634f
#define C2 (THRESH * INV_LN2F)   // validity threshold in log2 domain

// ---------------- Kernel 1: x = ALPHA * normalize(inputs); sq[i] = sum(x[i]^2) ----------------
__global__ __launch_bounds__(128) void normalize_kernel(const float* __restrict__ in,
                                                        float* __restrict__ x,
                                                        float* __restrict__ sq) {
    int row = blockIdx.x;
    int tid = threadIdx.x;               // 128 threads
    const float* r = in + (size_t)row * D;
    float p = 0.f;
    for (int d = tid; d < D; d += 128) { float v = r[d]; p += v * v; }
    __shared__ float red[128];
    red[tid] = p; __syncthreads();
    for (int s = 64; s > 0; s >>= 1) { if (tid < s) red[tid] += red[tid + s]; __syncthreads(); }
    float scale = ALPHA / sqrtf(red[0]);
    __syncthreads();
    float q = 0.f;
    for (int d = tid; d < D; d += 128) {
        float v = r[d] * scale;
        x[(size_t)row * D + d] = v;
        q += v * v;
    }
    red[tid] = q; __syncthreads();
    for (int s = 64; s > 0; s >>= 1) { if (tid < s) red[tid] += red[tid + s]; __syncthreads(); }
    if (tid == 0) sq[row] = red[0];
}

// ---------------- Kernel 2: dist[i][j] = sq[i] + sq[j] - 2 * dot(x_i, x_j) ----------------
// fp32 tile GEMM: 128x128 block tile, 256 threads, 8x8 per thread, BK=16,
// single LDS buffer + register prefetch of next k-tile.
#define BM 128
#define BN 128
#define BK 16

__global__ __launch_bounds__(256) void gemm_dist_kernel(const float* __restrict__ x,
                                                        const float* __restrict__ sq,
                                                        float* __restrict__ dist) {
    __shared__ float As[BK][BM + 4];   // [k][m]; +4 keeps rows 16B-aligned
    __shared__ float Bs[BK][BN + 4];
    int bi = blockIdx.y, bj = blockIdx.x;
    int tid = threadIdx.x;
    int tx = tid & 15, ty = tid >> 4;  // 16x16 thread grid, each 8x8 elements

    int lr = tid >> 2;                 // staging row 0..63 (and +64)
    int lk = (tid & 3) * 4;            // staging k-seg 0,4,8,12

    const float* aB  = x + ((size_t)(bi * BM + lr)) * D + lk;
    const float* aB2 = aB + (size_t)64 * D;
    const float* bB  = x + ((size_t)(bj * BN + lr)) * D + lk;
    const float* bB2 = bB + (size_t)64 * D;

    float acc[8][8] = {};

    float4 a0 = *(const float4*)(aB);
    float4 a1 = *(const float4*)(aB2);
    float4 b0 = *(const float4*)(bB);
    float4 b1 = *(const float4*)(bB2);

    for (int k0 = 0; k0 < D; k0 += BK) {
        As[lk + 0][lr]      = a0.x; As[lk + 1][lr]      = a0.y;
        As[lk + 2][lr]      = a0.z; As[lk + 3][lr]      = a0.w;
        As[lk + 0][lr + 64] = a1.x; As[lk + 1][lr + 64] = a1.y;
        As[lk + 2][lr + 64] = a1.z; As[lk + 3][lr + 64] = a1.w;
        Bs[lk + 0][lr]      = b0.x; Bs[lk + 1][lr]      = b0.y;
        Bs[lk + 2][lr]      = b0.z; Bs[lk + 3][lr]      = b0.w;
        Bs[lk + 0][lr + 64] = b1.x; Bs[lk + 1][lr + 64] = b1.y;
        Bs[lk + 2][lr + 64] = b1.z; Bs[lk + 3][lr + 64] = b1.w;
        __syncthreads();
        if (k0 + BK < D) {             // prefetch next tile; latency hidden by compute below
            a0 = *(const float4*)(aB + k0 + BK);
            a1 = *(const float4*)(aB2 + k0 + BK);
            b0 = *(const float4*)(bB + k0 + BK);
            b1 = *(const float4*)(bB2 + k0 + BK);
        }
        #pragma unroll
        for (int k = 0; k < BK; ++k) {
            float4 af0 = *(const float4*)&As[k][ty * 8];
            float4 af1 = *(const float4*)&As[k][ty * 8 + 4];
            float4 bf0 = *(const float4*)&Bs[k][tx * 8];
            float4 bf1 = *(const float4*)&Bs[k][tx * 8 + 4];
            float a[8] = {af0.x, af0.y, af0.z, af0.w, af1.x, af1.y, af1.z, af1.w};
            float b[8] = {bf0.x, bf0.y, bf0.z, bf0.w, bf1.x, bf1.y, bf1.z, bf1.w};
            #pragma unroll
            for (int i = 0; i < 8; ++i)
                #pragma unroll
                for (int j = 0; j < 8; ++j)
                    acc[i][j] = fmaf(a[i], b[j], acc[i][j]);
        }
        __syncthreads();
    }

    int row0 = bi * BM + ty * 8;
    int col0 = bj * BN + tx * 8;
    float sj[8];
    #pragma unroll
    for (int j = 0; j < 8; ++j) sj[j] = sq[col0 + j];
    #pragma unroll
    for (int i = 0; i < 8; ++i) {
        float si = sq[row0 + i];
        float4 o0, o1;
        o0.x = si + sj[0] - 2.f * acc[i][0];
        o0.y = si + sj[1] - 2.f * acc[i][1];
        o0.z = si + sj[2] - 2.f * acc[i][2];
        o0.w = si + sj[3] - 2.f * acc[i][3];
        o1.x = si + sj[4] - 2.f * acc[i][4];
        o1.y = si + sj[5] - 2.f * acc[i][5];
        o1.z = si + sj[6] - 2.f * acc[i][6];
        o1.w = si + sj[7] - 2.f * acc[i][7];
        *(float4*)&dist[(size_t)(row0 + i) * N + col0]     = o0;
        *(float4*)&dist[(size_t)(row0 + i) * N + col0 + 4] = o1;
    }
}

// ---------------- Kernel 3: per-row triplet reduction (no atomics) ----------------
// rowres[i] = {s2_sum (log2-domain), cnt, psum, nsum}
__global__ __launch_bounds__(256) void triplet_kernel(const float* __restrict__ dist,
                                                      float4* __restrict__ rowres) {
    int i = blockIdx.x;
    int tid = threadIdx.x;
    int cs = (i >> 3) << 3;            // class block start (K=8)
    const float* drow = dist + (size_t)i * N;

    __shared__ float pos[M];
    if (tid == 0) {
        int c = 0;
        for (int j = cs; j < cs + KC; ++j)
            if (j != i) pos[c++] = drow[j];
    }
    __syncthreads();
    float p[M], ep[M];
    #pragma unroll
    for (int k = 0; k < M; ++k) { p[k] = pos[k]; ep[k] = __expf(p[k]); }

    float s2 = 0.f, nsum = 0.f;
    unsigned cnt = 0;
    for (int j = tid; j < N; j += 256) {
        if (j >= cs && j < cs + KC) continue;
        float neg = drow[j];
        nsum += neg;
        float en = __expf(-neg);
        #pragma unroll
        for (int k = 0; k < M; ++k) {
            float e = ep[k] * en;
            float l = __log2f(1.f + e);
            if (l > C2) { cnt++; s2 += l; }
        }
    }

    __shared__ float rs[256];
    __shared__ float rn[256];
    __shared__ unsigned rc[256];
    rs[tid] = s2; rn[tid] = nsum; rc[tid] = cnt;
    __syncthreads();
    for (int st = 128; st > 0; st >>= 1) {
        if (tid < st) { rs[tid] += rs[tid + st]; rn[tid] += rn[tid + st]; rc[tid] += rc[tid + st]; }
        __syncthreads();
    }
    if (tid == 0) {
        float psum = 0.f;
        #pragma unroll
        for (int k = 0; k < M; ++k) psum += p[k];
        rowres[i] = make_float4(rs[0], (float)rc[0], psum, rn[0]);
    }
}

// ---------------- Kernel 4: deterministic final reduction + scalars ----------------
__global__ __launch_bounds__(256) void final_reduce_kernel(const float4* __restrict__ rowres,
                                                           float* __restrict__ out) {
    int tid = threadIdx.x;
    double srm = 0.0, ps = 0.0, ns = 0.0;
    unsigned long long tot = 0; unsigned zr = 0;
    for (int i = tid; i < N; i += 256) {
        float4 r = rowres[i];
        unsigned c = (unsigned)r.y;
        if (c > 0) {
            float row_mean = r.x * LN2F / (float)c;   // match per-row fp32 mean
            srm += (double)row_mean;
            tot += c;
        } else {
            zr++;
        }
        ps += (double)r.z;
        ns += (double)r.w;
    }
    __shared__ double d0[256], d1[256], d2[256];
    __shared__ unsigned long long dt[256];
    __shared__ unsigned dz[256];
    d0[tid] = srm; d1[tid] = ps; d2[tid] = ns; dt[tid] = tot; dz[tid] = zr;
    __syncthreads();
    for (int st = 128; st > 0; st >>= 1) {
        if (tid < st) {
            d0[tid] += d0[tid + st]; d1[tid] += d1[tid + st]; d2[tid] += d2[tid + st];
            dt[tid] += dt[tid + st]; dz[tid] += dz[tid + st];
        }
        __syncthreads();
    }
    if (tid == 0) {
        unsigned long long total = dt[0];
        out[0] = (total > 0) ? (float)(d0[0] / (double)total) : 0.f;     // loss
        out[1] = (float)((double)dz[0] / (double)N);                      // accuracy
        out[2] = (float)(d1[0] / (double)((size_t)N * M));                // pos_d
        out[3] = (float)(d2[0] / (double)((size_t)N * NNEG));             // neg_d
    }
}

extern "C" void kernel_launch(void* const* d_in, const int* in_sizes, int n_in,
                              void* d_out, int out_size, void* d_ws, size_t ws_size,
                              hipStream_t stream) {
    const float* inputs = (const float*)d_in[0];
    // targets (d_in[1]) are guaranteed grouped: [0]*8,[1]*8,... — structure used directly.
    float* out = (float*)d_out;
    char* ws = (char*)d_ws;

    const size_t off_x    = 0;
    const size_t off_sq   = off_x + (size_t)N * D * sizeof(float);       // 4 MB
    const size_t off_dist = off_sq + (size_t)N * sizeof(float) + 4096;
    const size_t off_row  = off_dist + (size_t)N * N * sizeof(float);    // 16 MB
    const size_t needed   = off_row + (size_t)N * sizeof(float4);
    if (ws_size < needed) return;

    float*  x      = (float*)(ws + off_x);
    float*  sq     = (float*)(ws + off_sq);
    float*  dist   = (float*)(ws + off_dist);
    float4* rowres = (float4*)(ws + off_row);

    normalize_kernel<<<N, 128, 0, stream>>>(inputs, x, sq);
    gemm_dist_kernel<<<dim3(N / BN, N / BM), 256, 0, stream>>>(x, sq, dist);
    triplet_kernel<<<N, 256, 0, stream>>>(dist, rowres);
    final_reduce_kernel<<<1, 256, 0, stream>>>(rowres, out);
}

// Round 4
// 95.753 us; speedup vs baseline: 2.8164x; 1.4665x over previous
//
#include <hip/hip_runtime.h>
#include <hip/hip_bf16.h>
#include <math.h>

#define N 2048
#define D 512
#define KC 8            // instances per class
#define M (KC - 1)      // positives per row
#define NNEG (N - KC)   // negatives per row
#define ALPHA 4.0f
#define THRESH 0.693f
#define LN2F 0.6931471805599453f
#define INV_LN2F 1.4426950408889634f
#define C2 (THRESH * INV_LN2F)   // validity threshold in log2 domain

typedef unsigned short ushort_t;
using frag_ab = __attribute__((ext_vector_type(8))) short;   // 8 bf16 (4 VGPRs)
using frag_cd = __attribute__((ext_vector_type(4))) float;   // 4 fp32

// ---------------- Kernel 1: normalize -> bf16 x, fp32 sq ----------------
__global__ __launch_bounds__(128) void normalize_kernel(const float* __restrict__ in,
                                                        ushort_t* __restrict__ xb,
                                                        float* __restrict__ sq) {
    int row = blockIdx.x;
    int tid = threadIdx.x;               // 128 threads
    const float* r = in + (size_t)row * D;
    float p = 0.f;
    for (int d = tid; d < D; d += 128) { float v = r[d]; p += v * v; }
    __shared__ float red[128];
    red[tid] = p; __syncthreads();
    for (int s = 64; s > 0; s >>= 1) { if (tid < s) red[tid] += red[tid + s]; __syncthreads(); }
    float scale = ALPHA / sqrtf(red[0]);
    __syncthreads();
    float q = 0.f;
    for (int d = tid; d < D; d += 128) {
        float v = r[d] * scale;
        q += v * v;                                  // fp32 sq, pre-rounding (matches reference)
        __hip_bfloat16 h = __float2bfloat16(v);      // RNE
        xb[(size_t)row * D + d] = *(ushort_t*)&h;
    }
    red[tid] = q; __syncthreads();
    for (int s = 64; s > 0; s >>= 1) { if (tid < s) red[tid] += red[tid + s]; __syncthreads(); }
    if (tid == 0) sq[row] = red[0];
}

// ---------------- Kernel 2: dist = sq_i + sq_j - 2 * x.x^T via bf16 MFMA ----------------
// m97 pattern: 128x128 tile, 256 threads (4 waves, 2x2), BK=32, global_load_lds(16B),
// mfma_f32_16x16x32_bf16, each wave computes 64x64 (4x4 tiles of 16x16).
#define TM 128
#define TN 128
#define TK 32

__global__ __launch_bounds__(256) void gemm_dist_mfma(const ushort_t* __restrict__ xb,
                                                      const float* __restrict__ sq,
                                                      float* __restrict__ dist) {
    __shared__ ushort_t As[TM * TK];   // row-major [128][32] bf16, no pad (global_load_lds order)
    __shared__ ushort_t Bs[TN * TK];
    int tid  = threadIdx.x;
    int lane = tid & 63;
    int w    = tid >> 6;
    int wm   = w >> 1, wn = w & 1;     // 2x2 wave grid
    int quad = lane >> 4, l16 = lane & 15;
    int bi = blockIdx.y, bj = blockIdx.x;

    frag_cd acc[4][4];
    #pragma unroll
    for (int i = 0; i < 4; ++i)
        #pragma unroll
        for (int j = 0; j < 4; ++j)
            acc[i][j] = (frag_cd){0.f, 0.f, 0.f, 0.f};

    // Staging: tile = 128 rows x 32 k = 512 chunks of 16B; thread t handles chunks t and 256+t.
    // chunk c -> row c>>2, k-seg (c&3)*8. LDS dest = chunk*16 bytes: for wave w, instr q,
    // lanes cover chunks q*256 + w*64 + lane -> contiguous base + lane*16 (wave-uniform base).
    int c0 = tid, c1 = 256 + tid;
    int r0 = c0 >> 2, s0 = (c0 & 3) * 8;
    int r1 = c1 >> 2, s1 = (c1 & 3) * 8;
    const ushort_t* gA0 = xb + (size_t)(bi * TM + r0) * D + s0;
    const ushort_t* gA1 = xb + (size_t)(bi * TM + r1) * D + s1;
    const ushort_t* gB0 = xb + (size_t)(bj * TN + r0) * D + s0;
    const ushort_t* gB1 = xb + (size_t)(bj * TN + r1) * D + s1;
    ushort_t* lA0 = As + (size_t)c0 * 8;
    ushort_t* lA1 = As + (size_t)c1 * 8;
    ushort_t* lB0 = Bs + (size_t)c0 * 8;
    ushort_t* lB1 = Bs + (size_t)c1 * 8;

    // Fragment LDS addresses (a/b operand layout: row = l16 (+tile), k = quad*8..+8)
    int aoff[4], boff[4];
    #pragma unroll
    for (int i = 0; i < 4; ++i) {
        aoff[i] = (wm * 64 + i * 16 + l16) * TK + quad * 8;
        boff[i] = (wn * 64 + i * 16 + l16) * TK + quad * 8;
    }

    for (int k0 = 0; k0 < D; k0 += TK) {
        __builtin_amdgcn_global_load_lds((const __attribute__((address_space(1))) unsigned int*)(gA0 + k0),
                                         (__attribute__((address_space(3))) unsigned int*)lA0, 16, 0, 0);
        __builtin_amdgcn_global_load_lds((const __attribute__((address_space(1))) unsigned int*)(gA1 + k0),
                                         (__attribute__((address_space(3))) unsigned int*)lA1, 16, 0, 0);
        __builtin_amdgcn_global_load_lds((const __attribute__((address_space(1))) unsigned int*)(gB0 + k0),
                                         (__attribute__((address_space(3))) unsigned int*)lB0, 16, 0, 0);
        __builtin_amdgcn_global_load_lds((const __attribute__((address_space(1))) unsigned int*)(gB1 + k0),
                                         (__attribute__((address_space(3))) unsigned int*)lB1, 16, 0, 0);
        __syncthreads();   // drains vmcnt (global_load_lds) before LDS reads

        frag_ab a[4], b[4];
        #pragma unroll
        for (int i = 0; i < 4; ++i) {
            a[i] = *(const frag_ab*)&As[aoff[i]];
            b[i] = *(const frag_ab*)&Bs[boff[i]];
        }
        #pragma unroll
        for (int i = 0; i < 4; ++i)
            #pragma unroll
            for (int j = 0; j < 4; ++j)
                acc[i][j] = __builtin_amdgcn_mfma_f32_16x16x32_bf16(a[i], b[j], acc[i][j], 0, 0, 0);
        __syncthreads();
    }

    // Epilogue: C/D layout col = lane&15, row = quad*4 + reg  [m89/m91 verified]
    int row_base = bi * TM + wm * 64 + quad * 4;
    int col_base = bj * TN + wn * 64 + l16;
    #pragma unroll
    for (int j = 0; j < 4; ++j) {
        int col = col_base + j * 16;
        float sjv = sq[col];
        #pragma unroll
        for (int i = 0; i < 4; ++i) {
            int row = row_base + i * 16;
            #pragma unroll
            for (int r = 0; r < 4; ++r) {
                dist[(size_t)(row + r) * N + col] = sq[row + r] + sjv - 2.f * acc[i][j][r];
            }
        }
    }
}

// ---------------- Kernel 3: per-row triplet reduction (no atomics) ----------------
// rowres[i] = {s2_sum (log2-domain), cnt, psum, nsum}
__global__ __launch_bounds__(256) void triplet_kernel(const float* __restrict__ dist,
                                                      float4* __restrict__ rowres) {
    int i = blockIdx.x;
    int tid = threadIdx.x;
    int cs = (i >> 3) << 3;            // class block start (K=8)
    const float* drow = dist + (size_t)i * N;

    __shared__ float pos[M];
    if (tid == 0) {
        int c = 0;
        for (int j = cs; j < cs + KC; ++j)
            if (j != i) pos[c++] = drow[j];
    }
    __syncthreads();
    float p[M], ep[M];
    #pragma unroll
    for (int k = 0; k < M; ++k) { p[k] = pos[k]; ep[k] = __expf(p[k]); }

    float s2 = 0.f, nsum = 0.f;
    unsigned cnt = 0;
    for (int j = tid; j < N; j += 256) {
        if (j >= cs && j < cs + KC) continue;
        float neg = drow[j];
        nsum += neg;
        float en = __expf(-neg);
        #pragma unroll
        for (int k = 0; k < M; ++k) {
            float e = ep[k] * en;
            float l = __log2f(1.f + e);
            if (l > C2) { cnt++; s2 += l; }
        }
    }

    __shared__ float rs[256];
    __shared__ float rn[256];
    __shared__ unsigned rc[256];
    rs[tid] = s2; rn[tid] = nsum; rc[tid] = cnt;
    __syncthreads();
    for (int st = 128; st > 0; st >>= 1) {
        if (tid < st) { rs[tid] += rs[tid + st]; rn[tid] += rn[tid + st]; rc[tid] += rc[tid + st]; }
        __syncthreads();
    }
    if (tid == 0) {
        float psum = 0.f;
        #pragma unroll
        for (int k = 0; k < M; ++k) psum += p[k];
        rowres[i] = make_float4(rs[0], (float)rc[0], psum, rn[0]);
    }
}

// ---------------- Kernel 4: deterministic final reduction + scalars ----------------
__global__ __launch_bounds__(256) void final_reduce_kernel(const float4* __restrict__ rowres,
                                                           float* __restrict__ out) {
    int tid = threadIdx.x;
    double srm = 0.0, ps = 0.0, ns = 0.0;
    unsigned long long tot = 0; unsigned zr = 0;
    for (int i = tid; i < N; i += 256) {
        float4 r = rowres[i];
        unsigned c = (unsigned)r.y;
        if (c > 0) {
            float row_mean = r.x * LN2F / (float)c;
            srm += (double)row_mean;
            tot += c;
        } else {
            zr++;
        }
        ps += (double)r.z;
        ns += (double)r.w;
    }
    __shared__ double d0[256], d1[256], d2[256];
    __shared__ unsigned long long dt[256];
    __shared__ unsigned dz[256];
    d0[tid] = srm; d1[tid] = ps; d2[tid] = ns; dt[tid] = tot; dz[tid] = zr;
    __syncthreads();
    for (int st = 128; st > 0; st >>= 1) {
        if (tid < st) {
            d0[tid] += d0[tid + st]; d1[tid] += d1[tid + st]; d2[tid] += d2[tid + st];
            dt[tid] += dt[tid + st]; dz[tid] += dz[tid + st];
        }
        __syncthreads();
    }
    if (tid == 0) {
        unsigned long long total = dt[0];
        out[0] = (total > 0) ? (float)(d0[0] / (double)total) : 0.f;     // loss
        out[1] = (float)((double)dz[0] / (double)N);                      // accuracy
        out[2] = (float)(d1[0] / (double)((size_t)N * M));                // pos_d
        out[3] = (float)(d2[0] / (double)((size_t)N * NNEG));             // neg_d
    }
}

extern "C" void kernel_launch(void* const* d_in, const int* in_sizes, int n_in,
                              void* d_out, int out_size, void* d_ws, size_t ws_size,
                              hipStream_t stream) {
    const float* inputs = (const float*)d_in[0];
    // targets (d_in[1]) are grouped: [0]*8,[1]*8,... — structure used directly.
    float* out = (float*)d_out;
    char* ws = (char*)d_ws;

    const size_t off_xb   = 0;                                            // bf16 x: 2 MB
    const size_t off_sq   = off_xb + (size_t)N * D * sizeof(ushort_t);
    const size_t off_dist = off_sq + (size_t)N * sizeof(float) + 4096;    // align
    const size_t off_row  = off_dist + (size_t)N * N * sizeof(float);     // 16 MB
    const size_t needed   = off_row + (size_t)N * sizeof(float4);
    if (ws_size < needed) return;

    ushort_t* xb     = (ushort_t*)(ws + off_xb);
    float*    sq     = (float*)(ws + off_sq);
    float*    dist   = (float*)(ws + off_dist);
    float4*   rowres = (float4*)(ws + off_row);

    normalize_kernel<<<N, 128, 0, stream>>>(inputs, xb, sq);
    gemm_dist_mfma<<<dim3(N / TN, N / TM), 256, 0, stream>>>(xb, sq, dist);
    triplet_kernel<<<N, 256, 0, stream>>>(dist, rowres);
    final_reduce_kernel<<<1, 256, 0, stream>>>(rowres, out);
}